// Round 17
// baseline (292.969 us; speedup 1.0000x reference)
//
#include <hip/hip_runtime.h>

// pyGAMNet round 16 kernel (re-submit; R16 bench was a broker timeout).
// 8 rows/lane (halves per-CU LDS-pipe demand for W1 — R15 was LDS-bound at
// ~105us vs 69us VALU floor) + o-split {8,8,4} to cap live accumulators.
// 1024-thread blocks: 16 waves x 1 feature so the block's column window
// stays 64B (R8 lesson). Output tile aliases W1 LDS after a barrier.

constexpr int NCOLS = 64;
constexpr int NNUM  = 48;
constexpr int NCLS  = 32;
constexpr int H0N   = 40;
constexpr int H1N   = 20;

#define BLOCK 1024
#define RPB   512    // rows per block; row = row0 + q*64 + lane, q=0..7
#define NRG   256    // row-groups = 131072 / 512
#define TS    20     // tile stride (16 cols used; 16B-aligned)

// pool floats: w1s 12800 | wb0 1280 | b1s 320 | w2s 320 | b2s 16 = 14736
// tile (512*20=10240) aliases w1s after the post-compute barrier.
// cat cb (512) lives at +12800 (outside tile region).
#define POOL_F 14736

__global__ __launch_bounds__(BLOCK, 4)
void gam_kernel(const float* __restrict__ inp,
                const float* __restrict__ W0, const float* __restrict__ b0,
                const float* __restrict__ W1, const float* __restrict__ b1,
                const float* __restrict__ W2, const float* __restrict__ b2,
                const float* __restrict__ cbias,
                float* __restrict__ out)
{
    __shared__ __align__(16) float pool[POOL_F];

    const int t    = threadIdx.x;
    const int lane = t & 63;
    const int wv   = __builtin_amdgcn_readfirstlane(t >> 6);   // 0..15
    const int fg   = blockIdx.x >> 8;          // 0..3: 0-2 numeric, 3 cat
    const int rg   = blockIdx.x & (NRG - 1);
    const int row0 = rg * RPB;
    const float* __restrict__ rp = inp + (row0 + lane) * NCOLS;  // + q*4096
    float* tile = pool;                        // alias (used after barrier)

    if (fg < 3) {
        float* w1s = pool;                     // [16][40][20]
        float* wb0 = pool + 12800;             // [16][40][2] = {w0,b0}
        float* b1s = pool + 14080;             // [16][20]
        float* w2s = pool + 14400;             // [16][20]
        float* b2s = pool + 14720;             // [16]
        const int fbase = fg * 16;

        // ---- stage 16 features' weights (float4 reads, contiguous) ----
        {
            const float4* g1 = reinterpret_cast<const float4*>(W1 + fbase * H0N * H1N);
            float4* d1 = reinterpret_cast<float4*>(w1s);
            for (int i = t; i < 16 * H0N * H1N / 4; i += BLOCK) d1[i] = g1[i];
            for (int i = t; i < 16 * H0N; i += BLOCK) {
                wb0[2 * i]     = W0[fbase * H0N + i];
                wb0[2 * i + 1] = b0[fbase * H0N + i];
            }
            if (t < 16 * H1N / 4) {
                reinterpret_cast<float4*>(b1s)[t] =
                    reinterpret_cast<const float4*>(b1 + fbase * H1N)[t];
                reinterpret_cast<float4*>(w2s)[t] =
                    reinterpret_cast<const float4*>(W2 + fbase * H1N)[t];
            }
            if (t < 16) b2s[t] = b2[fbase + t];
        }
        __syncthreads();

        // ---- compute: wave wv owns feature fbase+wv; 8 rows/lane ----
        const float* __restrict__ wf1 = w1s + wv * (H0N * H1N);  // [k][20]
        const float* __restrict__ wbf = wb0 + wv * (H0N * 2);    // [k][2]
        const float* __restrict__ b1v = b1s + wv * H1N;
        const float* __restrict__ w2v = w2s + wv * H1N;

        float x[8];
        #pragma unroll
        for (int q = 0; q < 8; ++q) x[q] = rp[q * 4096 + fbase + wv];

        float oacc[8];
        {
            const float b2v = b2s[wv];
            #pragma unroll
            for (int q = 0; q < 8; ++q) oacc[q] = b2v;
        }

        // ---- pass A: outputs 0..7 (64 live accs) ----
        {
            float a[8][8];
            #pragma unroll
            for (int o = 0; o < 8; ++o) {
                const float bv = b1v[o];
                #pragma unroll
                for (int q = 0; q < 8; ++q) a[q][o] = bv;
            }
            #pragma unroll 4
            for (int k = 0; k < H0N; ++k) {
                const float2 wb = *reinterpret_cast<const float2*>(wbf + k * 2);
                float h[8];
                #pragma unroll
                for (int q = 0; q < 8; ++q)
                    h[q] = fmaxf(fmaf(x[q], wb.x, wb.y), 0.f);
                const float4 wA = *reinterpret_cast<const float4*>(wf1 + k * H1N + 0);
                const float4 wB = *reinterpret_cast<const float4*>(wf1 + k * H1N + 4);
                const float w[8] = {wA.x, wA.y, wA.z, wA.w, wB.x, wB.y, wB.z, wB.w};
                #pragma unroll
                for (int o = 0; o < 8; ++o)
                    #pragma unroll
                    for (int q = 0; q < 8; ++q)
                        a[q][o] = fmaf(h[q], w[o], a[q][o]);
            }
            #pragma unroll
            for (int o = 0; o < 8; ++o) {
                const float w = w2v[o];
                #pragma unroll
                for (int q = 0; q < 8; ++q)
                    oacc[q] = fmaf(fmaxf(a[q][o], 0.f), w, oacc[q]);
            }
        }
        // ---- pass B: outputs 8..15 ----
        {
            float a[8][8];
            #pragma unroll
            for (int o = 0; o < 8; ++o) {
                const float bv = b1v[8 + o];
                #pragma unroll
                for (int q = 0; q < 8; ++q) a[q][o] = bv;
            }
            #pragma unroll 4
            for (int k = 0; k < H0N; ++k) {
                const float2 wb = *reinterpret_cast<const float2*>(wbf + k * 2);
                float h[8];
                #pragma unroll
                for (int q = 0; q < 8; ++q)
                    h[q] = fmaxf(fmaf(x[q], wb.x, wb.y), 0.f);
                const float4 wA = *reinterpret_cast<const float4*>(wf1 + k * H1N + 8);
                const float4 wB = *reinterpret_cast<const float4*>(wf1 + k * H1N + 12);
                const float w[8] = {wA.x, wA.y, wA.z, wA.w, wB.x, wB.y, wB.z, wB.w};
                #pragma unroll
                for (int o = 0; o < 8; ++o)
                    #pragma unroll
                    for (int q = 0; q < 8; ++q)
                        a[q][o] = fmaf(h[q], w[o], a[q][o]);
            }
            #pragma unroll
            for (int o = 0; o < 8; ++o) {
                const float w = w2v[8 + o];
                #pragma unroll
                for (int q = 0; q < 8; ++q)
                    oacc[q] = fmaf(fmaxf(a[q][o], 0.f), w, oacc[q]);
            }
        }
        // ---- pass C: outputs 16..19 (32 live accs) ----
        {
            float a[8][4];
            #pragma unroll
            for (int o = 0; o < 4; ++o) {
                const float bv = b1v[16 + o];
                #pragma unroll
                for (int q = 0; q < 8; ++q) a[q][o] = bv;
            }
            #pragma unroll 4
            for (int k = 0; k < H0N; ++k) {
                const float2 wb = *reinterpret_cast<const float2*>(wbf + k * 2);
                float h[8];
                #pragma unroll
                for (int q = 0; q < 8; ++q)
                    h[q] = fmaxf(fmaf(x[q], wb.x, wb.y), 0.f);
                const float4 wA = *reinterpret_cast<const float4*>(wf1 + k * H1N + 16);
                const float w[4] = {wA.x, wA.y, wA.z, wA.w};
                #pragma unroll
                for (int o = 0; o < 4; ++o)
                    #pragma unroll
                    for (int q = 0; q < 8; ++q)
                        a[q][o] = fmaf(h[q], w[o], a[q][o]);
            }
            #pragma unroll
            for (int o = 0; o < 4; ++o) {
                const float w = w2v[16 + o];
                #pragma unroll
                for (int q = 0; q < 8; ++q)
                    oacc[q] = fmaf(fmaxf(a[q][o], 0.f), w, oacc[q]);
            }
        }

        __syncthreads();   // all weight reads done; tile may overwrite w1s
        #pragma unroll
        for (int q = 0; q < 8; ++q)
            tile[(q * 64 + lane) * TS + wv] = oacc[q];
        __syncthreads();

        // ---- epilogue: 512 rows x 16 cols, float4 stores (64B/row/block) ----
        #pragma unroll
        for (int it = 0; it < 2; ++it) {
            const int idx = it * BLOCK + t;
            const int r = idx >> 2, c4 = (idx & 3) * 4;
            float4 v = *reinterpret_cast<const float4*>(&tile[r * TS + c4]);
            *reinterpret_cast<float4*>(out + (row0 + r) * NCOLS + fg * 16 + c4) = v;
        }
    } else {
        // ---- categorical: cols 48..63; wave wv = cat feature wv ----
        float* cb = pool + 12800;
        if (t < 16 * NCLS) cb[t] = cbias[t];
        __syncthreads();

        #pragma unroll
        for (int q = 0; q < 8; ++q) {
            const int idx = (int)rp[q * 4096 + NNUM + wv];
            tile[(q * 64 + lane) * TS + wv] = cb[wv * NCLS + idx];
        }
        __syncthreads();

        #pragma unroll
        for (int it = 0; it < 2; ++it) {
            const int idx = it * BLOCK + t;
            const int r = idx >> 2, c4 = (idx & 3) * 4;
            float4 v = *reinterpret_cast<const float4*>(&tile[r * TS + c4]);
            *reinterpret_cast<float4*>(out + (row0 + r) * NCOLS + NNUM + c4) = v;
        }
    }
}

extern "C" void kernel_launch(void* const* d_in, const int* in_sizes, int n_in,
                              void* d_out, int out_size, void* d_ws, size_t ws_size,
                              hipStream_t stream) {
    const float* inp   = (const float*)d_in[0];
    const float* W0    = (const float*)d_in[1];
    const float* b0    = (const float*)d_in[2];
    const float* W1    = (const float*)d_in[3];
    const float* b1    = (const float*)d_in[4];
    const float* W2    = (const float*)d_in[5];
    const float* b2    = (const float*)d_in[6];
    const float* cbias = (const float*)d_in[7];
    float* out = (float*)d_out;

    dim3 grid(4 * NRG);   // 3 numeric fgroups + 1 cat, rg fastest: 1024 blocks
    dim3 block(BLOCK);
    gam_kernel<<<grid, block, 0, stream>>>(inp, W0, b0, W1, b1, W2, b2, cbias, out);
}